// Round 6
// baseline (225.174 us; speedup 1.0000x reference)
//
#include <hip/hip_runtime.h>
#include <float.h>
#include <math.h>

typedef __attribute__((ext_vector_type(8))) short short8;
typedef __attribute__((ext_vector_type(4))) float f32x4;
typedef __attribute__((ext_vector_type(4))) unsigned short u16x4;
typedef unsigned short u16;
typedef unsigned int u32;

constexpr int B_ = 64, S_ = 512, N_ = 128, D_ = 768;

// ---------------------------------------------------------------------------
__device__ inline u16 bf16_rne(float x) {
    u32 u = __builtin_bit_cast(u32, x);
    u += 0x7FFFu + ((u >> 16) & 1u);
    return (u16)(u >> 16);
}
__device__ inline float bf2f(u16 h) {
    u32 u = ((u32)h) << 16;
    return __builtin_bit_cast(float, u);
}
__device__ inline void split2(float x, u16& h, u16& l) {
    h = bf16_rne(x);
    l = bf16_rne(x - bf2f(h));
}

__device__ inline void gload_lds16(const u16* g, u16* s) {
    __builtin_amdgcn_global_load_lds(
        (const __attribute__((address_space(1))) u32*)g,
        (__attribute__((address_space(3))) u32*)s, 16, 0, 0);
}

// ---------------------------------------------------------------------------
__global__ __launch_bounds__(192)
void span_split_kernel(const float* __restrict__ se, const int* __restrict__ spans,
                       u16* __restrict__ th, u16* __restrict__ tl) {
    const int bn = blockIdx.x;
    const int b  = bn >> 7;
    const int s  = spans[bn * 2 + 0];
    const int e  = spans[bn * 2 + 1];
    const float* base = se + (size_t)b * S_ * D_;
    const int d4 = threadIdx.x;
    float4 acc = make_float4(0.f, 0.f, 0.f, 0.f);
    for (int r = s + 1; r <= e; ++r) {
        const float4 v = reinterpret_cast<const float4*>(base + (size_t)r * D_)[d4];
        acc.x += v.x; acc.y += v.y; acc.z += v.z; acc.w += v.w;
    }
    u16x4 hv, lv;
    u16 hh, ll;
    split2(acc.x, hh, ll); hv[0] = hh; lv[0] = ll;
    split2(acc.y, hh, ll); hv[1] = hh; lv[1] = ll;
    split2(acc.z, hh, ll); hv[2] = hh; lv[2] = ll;
    split2(acc.w, hh, ll); hv[3] = hh; lv[3] = ll;
    *(u16x4*)(th + (size_t)bn * D_ + d4 * 4) = hv;
    *(u16x4*)(tl + (size_t)bn * D_ + d4 * 4) = lv;
}

// ---------------------------------------------------------------------------
__global__ __launch_bounds__(192)
void target_max_kernel(const float* __restrict__ se, const int* __restrict__ tspan,
                       float* __restrict__ tmax) {
    const int b = blockIdx.x;
    const int s = tspan[b * 2 + 0];
    const int e = tspan[b * 2 + 1];
    const float* base = se + (size_t)b * S_ * D_;
    const int d4 = threadIdx.x;
    float4 m = make_float4(-FLT_MAX, -FLT_MAX, -FLT_MAX, -FLT_MAX);
    for (int r = s; r < e; ++r) {
        const float4 v = reinterpret_cast<const float4*>(base + (size_t)r * D_)[d4];
        m.x = fmaxf(m.x, v.x); m.y = fmaxf(m.y, v.y);
        m.z = fmaxf(m.z, v.z); m.w = fmaxf(m.w, v.w);
    }
    reinterpret_cast<float4*>(tmax + (size_t)b * D_)[d4] = m;
}

// ---------------------------------------------------------------------------
// adj = clamp(dg+dg1,1) -> bf16 (exact {0,1}) [b][n][k]; invden = 1/(rowsum+1e-7)
__global__ __launch_bounds__(128)
void adj_kernel(const float* __restrict__ dg, const float* __restrict__ dg1,
                u16* __restrict__ adj, float* __restrict__ invden) {
    const int row = blockIdx.x;
    const int t   = threadIdx.x;
    const size_t idx = (size_t)row * N_ + t;
    float a = dg[idx] + dg1[idx];
    a = (a >= 1.f) ? 1.f : a;
    adj[idx] = bf16_rne(a);
    float w = a;
    #pragma unroll
    for (int off = 32; off; off >>= 1) w += __shfl_down(w, off, 64);
    __shared__ float ssum[2];
    if ((t & 63) == 0) ssum[t >> 6] = w;
    __syncthreads();
    if (t == 0) invden[row] = 1.f / (ssum[0] + ssum[1] + 1e-7f);
}

// ---------------------------------------------------------------------------
// Weights: W[k][n] (768x768) -> WT[n][k] split bf16 hi/lo. blockIdx.z = matrix.
__global__ __launch_bounds__(256)
void wsplit_kernel(const float* __restrict__ W0, const float* __restrict__ W1,
                   const float* __restrict__ W2, const float* __restrict__ W3,
                   u16* __restrict__ wth, u16* __restrict__ wtl) {
    __shared__ float t[64][65];
    const int mi = blockIdx.z;
    const float* W = (mi == 0) ? W0 : (mi == 1) ? W1 : (mi == 2) ? W2 : W3;
    const int k0 = blockIdx.y * 64, n0 = blockIdx.x * 64;
    #pragma unroll 4
    for (int it = 0; it < 16; ++it) {
        const int lin = it * 256 + threadIdx.x;
        const int r = lin >> 6, c = lin & 63;
        t[r][c] = W[(size_t)(k0 + r) * D_ + n0 + c];
    }
    __syncthreads();
    u16* oh = wth + (size_t)mi * D_ * D_;
    u16* ol = wtl + (size_t)mi * D_ * D_;
    #pragma unroll 4
    for (int it = 0; it < 16; ++it) {
        const int lin = it * 256 + threadIdx.x;
        const int r = lin >> 6, c = lin & 63;
        u16 h, l; split2(t[c][r], h, l);
        oh[(size_t)(n0 + r) * D_ + k0 + c] = h;
        ol[(size_t)(n0 + r) * D_ + k0 + c] = l;
    }
}

// ---------------------------------------------------------------------------
// Fused split-bf16 GEMM, 256x96 tile, 512 threads (8 waves 4x2), grid = 256
// blocks = exactly 1/CU. Triple-buffered BK=32 staging with a SINGLE barrier
// per K-step and counted vmcnt (loads 2 tiles deep, never drained mid-loop).
// LDS: 3 x 22528 u16 buffers (132 KB). Buffer: A 32 groups | B 12 groups,
// group = 8 rows x 8 chunks(16B), hi/lo interleaved, chunk p = q ^ (row&7)
// (XOR pre-applied on the per-lane GLOBAL source; LDS dest stays linear).
// MODE 0: store relu(H) split hi/lo row-major.
// MODE 1: phase 2: out = relu((adj[b]@H)*invden + bias) + X_in for the TWO
//   batches in this block; adj held in VGPRs (16 x short8), H^T staged into
//   dead tri-buffer LDS (2 x 96 x 128, swizzled), hi pass then lo pass.
template<int MODE>
__global__ __launch_bounds__(512, 2)
void gemm_fused(const u16* __restrict__ Ah, const u16* __restrict__ Al,
                const u16* __restrict__ Bh, const u16* __restrict__ Bl,
                const u16* __restrict__ ADJ, const float* __restrict__ invden,
                const float* __restrict__ bias,
                u16* __restrict__ Oh, u16* __restrict__ Ol) {
    __shared__ u16 lds[67584];          // 3 x 22528 u16 = 132 KB
    const int tid  = threadIdx.x;
    const int lane = tid & 63, w = tid >> 6;     // 8 waves
    const int wr = w >> 1, wc = w & 1;           // 4 row-waves x 2 col-waves
    const int lr = lane & 15, lh = lane >> 4;

    const int bid = blockIdx.x;                  // 32 row-panels x 8 col-panels
    const int bnb = bid & 7, bmb = bid >> 3;
    const int bm = bmb * 256, bn = bnb * 96;

    // --- staging setup: 44 groups (32 A + 12 B), waves get 6/6/6/6/5/5/5/5 ---
    const int lr3 = lane >> 3;                   // row within 8-row group
    const int q   = (lane & 7) ^ lr3;            // logical chunk for this lane
    const int qk  = (q & 3) * 8;                 // k-offset within BK=32
    const int g0  = (w < 4) ? w * 6 : 24 + (w - 4) * 5;
    const int nld = (w < 4) ? 6 : 5;
    const u16* gp[6];
    #pragma unroll
    for (int i = 0; i < 6; ++i) {
        int g = g0 + i; if (g > 43) g = 43;
        const bool isA = g < 32;
        const u16* base = isA ? ((q & 4) ? Al : Ah) : ((q & 4) ? Bl : Bh);
        const int row = isA ? (bm + g * 8 + lr3) : (bn + (g - 32) * 8 + lr3);
        gp[i] = base + (size_t)row * 768 + qk;
    }

    u16* const bufs[3] = {lds, lds + 22528, lds + 45056};

    auto STAGE = [&](int t) {
        u16* b = bufs[t % 3];
        #pragma unroll
        for (int i = 0; i < 6; ++i)
            if (i < nld) gload_lds16(gp[i] + t * 32, b + (g0 + i) * 512);
    };

    f32x4 acc[4][3];
    #pragma unroll
    for (int i = 0; i < 4; ++i)
        #pragma unroll
        for (int j = 0; j < 3; ++j)
            acc[i][j] = (f32x4){0.f, 0.f, 0.f, 0.f};

    STAGE(0);
    STAGE(1);

    const int r7  = lr & 7;
    const int pHi = (lh ^ r7) << 3;
    const int pLo = ((4 | lh) ^ r7) << 3;

    #pragma unroll
    for (int t = 0; t < 24; ++t) {
        if (t < 23) {
            if (w < 4) asm volatile("s_waitcnt vmcnt(6)" ::: "memory");
            else       asm volatile("s_waitcnt vmcnt(5)" ::: "memory");
        } else {
            asm volatile("s_waitcnt vmcnt(0)" ::: "memory");
        }
        __builtin_amdgcn_s_barrier();            // all waves: tile t landed,
        __builtin_amdgcn_sched_barrier(0);       // iter t-1 reads complete
        if (t < 22) STAGE(t + 2);                // safe: overwrites buf (t-1)%3

        const u16* L = bufs[t % 3];
        short8 ah[4], al[4], bh4[3], bl4[3];
        #pragma unroll
        for (int f = 0; f < 4; ++f) {
            const int ra = (wr * 64 + f * 16 + lr) * 64;
            ah[f] = *(const short8*)&L[ra + pHi];
            al[f] = *(const short8*)&L[ra + pLo];
        }
        #pragma unroll
        for (int f = 0; f < 3; ++f) {
            const int rb = 16384 + (wc * 48 + f * 16 + lr) * 64;
            bh4[f] = *(const short8*)&L[rb + pHi];
            bl4[f] = *(const short8*)&L[rb + pLo];
        }
        #pragma unroll
        for (int mf = 0; mf < 4; ++mf)
            #pragma unroll
            for (int nf = 0; nf < 3; ++nf) {
                acc[mf][nf] = __builtin_amdgcn_mfma_f32_16x16x32_bf16(ah[mf], bh4[nf], acc[mf][nf], 0, 0, 0);
                acc[mf][nf] = __builtin_amdgcn_mfma_f32_16x16x32_bf16(ah[mf], bl4[nf], acc[mf][nf], 0, 0, 0);
                acc[mf][nf] = __builtin_amdgcn_mfma_f32_16x16x32_bf16(al[mf], bh4[nf], acc[mf][nf], 0, 0, 0);
            }
    }

    if (MODE == 0) {
        #pragma unroll
        for (int mf = 0; mf < 4; ++mf)
            #pragma unroll
            for (int r = 0; r < 4; ++r) {
                const int row = bm + wr * 64 + mf * 16 + lh * 4 + r;
                #pragma unroll
                for (int nf = 0; nf < 3; ++nf) {
                    const int c = bn + wc * 48 + nf * 16 + lr;
                    const float v = fmaxf(acc[mf][nf][r], 0.f);
                    u16 h, l; split2(v, h, l);
                    const size_t gi = (size_t)row * 768 + c;
                    Oh[gi] = h; Ol[gi] = l;
                }
            }
        return;
    }

    // ---------------- MODE 1: phase 2 (dual-batch adjacency GEMM) -----------
    const int bb = wr >> 1;                      // batch within block (0/1)
    const int nh = wr & 1;                       // node half (0/1)
    const int bglob = bmb * 2 + bb;
    const u16* adjb = ADJ + (size_t)bglob * (N_ * N_);
    short8 adjr[16];                             // adj rows for my 64 nodes
    #pragma unroll
    for (int mf = 0; mf < 4; ++mf)
        #pragma unroll
        for (int ks = 0; ks < 4; ++ks)
            adjr[mf * 4 + ks] = *(const short8*)(adjb +
                (size_t)(nh * 64 + mf * 16 + lr) * 128 + ks * 32 + lh * 8);

    u16* hwT = lds;                              // [2][96 c][128 node] swizzled
    u16x4 lv[4][3];
    #pragma unroll
    for (int mf = 0; mf < 4; ++mf) {
        const int node0 = nh * 64 + mf * 16 + lh * 4;
        #pragma unroll
        for (int nf = 0; nf < 3; ++nf) {
            const int c = wc * 48 + nf * 16 + lr;
            u16x4 hv;
            #pragma unroll
            for (int r = 0; r < 4; ++r) {
                u16 h, l; split2(acc[mf][nf][r], h, l);
                hv[r] = h; lv[mf][nf][r] = l;
            }
            *(u16x4*)&hwT[bb * 12288 + c * 128 + (((node0 >> 3) ^ (c & 7)) << 3) + (node0 & 7)] = hv;
        }
    }
    asm volatile("s_waitcnt lgkmcnt(0)" ::: "memory");
    __builtin_amdgcn_s_barrier();
    __builtin_amdgcn_sched_barrier(0);

    f32x4 acc2[4][3];
    #pragma unroll
    for (int i = 0; i < 4; ++i)
        #pragma unroll
        for (int j = 0; j < 3; ++j)
            acc2[i][j] = (f32x4){0.f, 0.f, 0.f, 0.f};

    #pragma unroll
    for (int pass = 0; pass < 2; ++pass) {
        if (pass == 1) {
            #pragma unroll
            for (int mf = 0; mf < 4; ++mf) {
                const int node0 = nh * 64 + mf * 16 + lh * 4;
                #pragma unroll
                for (int nf = 0; nf < 3; ++nf) {
                    const int c = wc * 48 + nf * 16 + lr;
                    *(u16x4*)&hwT[bb * 12288 + c * 128 + (((node0 >> 3) ^ (c & 7)) << 3) + (node0 & 7)] = lv[mf][nf];
                }
            }
            asm volatile("s_waitcnt lgkmcnt(0)" ::: "memory");
            __builtin_amdgcn_s_barrier();
            __builtin_amdgcn_sched_barrier(0);
        }
        #pragma unroll
        for (int ks = 0; ks < 4; ++ks) {
            short8 bf[3];
            #pragma unroll
            for (int f = 0; f < 3; ++f) {
                const int c = wc * 48 + f * 16 + lr;
                bf[f] = *(const short8*)&hwT[bb * 12288 + c * 128 + (((ks * 4 + lh) ^ (c & 7)) << 3)];
            }
            #pragma unroll
            for (int mf = 0; mf < 4; ++mf)
                #pragma unroll
                for (int nf = 0; nf < 3; ++nf)
                    acc2[mf][nf] = __builtin_amdgcn_mfma_f32_16x16x32_bf16(adjr[mf * 4 + ks], bf[nf], acc2[mf][nf], 0, 0, 0);
        }
        if (pass == 0) {
            asm volatile("s_waitcnt lgkmcnt(0)" ::: "memory");
            __builtin_amdgcn_s_barrier();
            __builtin_amdgcn_sched_barrier(0);
        }
    }

    // epilogue: out = relu(acc2*inv + bias) + X_in; split; store
    #pragma unroll
    for (int mf = 0; mf < 4; ++mf)
        #pragma unroll
        for (int r = 0; r < 4; ++r) {
            const int node = nh * 64 + mf * 16 + lh * 4 + r;
            const float inv = invden[bglob * N_ + node];
            const size_t rowbase = ((size_t)bglob * N_ + node) * 768 + bn;
            #pragma unroll
            for (int nf = 0; nf < 3; ++nf) {
                const int c = wc * 48 + nf * 16 + lr;
                float v = fmaxf(acc2[mf][nf][r] * inv + bias[bn + c], 0.f);
                const size_t gi = rowbase + c;
                v += bf2f(Ah[gi]) + bf2f(Al[gi]);   // residual = A-source
                u16 h, l; split2(v, h, l);
                Oh[gi] = h; Ol[gi] = l;
            }
        }
}

// ---------------------------------------------------------------------------
__global__ __launch_bounds__(192)
void gcn_target_kernel(const u16* __restrict__ Xh, const u16* __restrict__ Xl,
                       const int* __restrict__ gspan, float* __restrict__ gt) {
    const int b = blockIdx.x;
    const int s = gspan[b * 2 + 0];
    const int e = gspan[b * 2 + 1];
    const int d4 = threadIdx.x;
    float4 acc = make_float4(0.f, 0.f, 0.f, 0.f);
    for (int n = s; n < e; ++n) {
        const size_t base = (size_t)(b * N_ + n) * D_ + d4 * 4;
        const u16x4 h = *(const u16x4*)(Xh + base);
        const u16x4 l = *(const u16x4*)(Xl + base);
        acc.x += bf2f(h[0]) + bf2f(l[0]);
        acc.y += bf2f(h[1]) + bf2f(l[1]);
        acc.z += bf2f(h[2]) + bf2f(l[2]);
        acc.w += bf2f(h[3]) + bf2f(l[3]);
    }
    reinterpret_cast<float4*>(gt + (size_t)b * D_)[d4] = acc;
}

// ---------------------------------------------------------------------------
__global__ __launch_bounds__(256)
void head_kernel(const float* __restrict__ tmax, const float* __restrict__ gt,
                 const float* __restrict__ fcW, const float* __restrict__ fcb,
                 float* __restrict__ out) {
    const int b = blockIdx.x;
    const int t = threadIdx.x;
    float p0 = 0.f, p1 = 0.f, p2 = 0.f;
    for (int i = t; i < 2 * D_; i += 256) {
        const float v = (i < D_) ? tmax[(size_t)b * D_ + i] : gt[(size_t)b * D_ + i - D_];
        p0 += v * fcW[i * 3 + 0];
        p1 += v * fcW[i * 3 + 1];
        p2 += v * fcW[i * 3 + 2];
    }
    #pragma unroll
    for (int off = 32; off; off >>= 1) {
        p0 += __shfl_down(p0, off, 64);
        p1 += __shfl_down(p1, off, 64);
        p2 += __shfl_down(p2, off, 64);
    }
    __shared__ float red[4][3];
    const int wv = t >> 6;
    if ((t & 63) == 0) { red[wv][0] = p0; red[wv][1] = p1; red[wv][2] = p2; }
    __syncthreads();
    if (t == 0) {
        #pragma unroll
        for (int o = 0; o < 3; ++o) {
            const float s = red[0][o] + red[1][o] + red[2][o] + red[3][o] + fcb[o];
            out[b * 3 + o] = tanhf(s);
        }
    }
}

// ---------------------------------------------------------------------------
extern "C" void kernel_launch(void* const* d_in, const int* in_sizes, int n_in,
                              void* d_out, int out_size, void* d_ws, size_t ws_size,
                              hipStream_t stream) {
    const float* se   = (const float*)d_in[0];
    const float* dg   = (const float*)d_in[1];
    const float* dg1  = (const float*)d_in[2];
    const float* Wp   = (const float*)d_in[3];
    const float* Wg[3] = {(const float*)d_in[4], (const float*)d_in[6], (const float*)d_in[8]};
    const float* bg[3] = {(const float*)d_in[5], (const float*)d_in[7], (const float*)d_in[9]};
    const float* fcW  = (const float*)d_in[10];
    const float* fcb  = (const float*)d_in[11];
    const int*   tspan  = (const int*)d_in[12];
    const int*   nspans = (const int*)d_in[13];
    const int*   gspan  = (const int*)d_in[14];
    float* out = (float*)d_out;

    // workspace layout (u16 units unless noted)
    u16* us   = (u16*)d_ws;
    u16* X0h  = us;                        // 8192*768 each
    u16* X0l  = X0h + 6291456;
    u16* X1h  = X0l + 6291456;
    u16* X1l  = X1h + 6291456;
    u16* TH   = X1l + 6291456;             // tmps hi/lo
    u16* TL   = TH  + 6291456;
    u16* WTh  = TL  + 6291456;             // 4*768*768
    u16* WTl  = WTh + 2359296;
    u16* ADJ  = WTl + 2359296;             // 64*128*128
    float* INV = (float*)(ADJ + 1048576);  // 8192
    float* TMX = INV + 8192;               // 64*768
    float* GT  = TMX + 49152;              // 64*768

    // Stage A: ragged prep
    span_split_kernel<<<B_ * N_, 192, 0, stream>>>(se, nspans, TH, TL);
    target_max_kernel<<<B_, 192, 0, stream>>>(se, tspan, TMX);
    adj_kernel<<<B_ * N_, 128, 0, stream>>>(dg, dg1, ADJ, INV);
    wsplit_kernel<<<dim3(12, 12, 4), 256, 0, stream>>>(Wp, Wg[0], Wg[1], Wg[2], WTh, WTl);

    // Stage B: X0 = relu(tmps @ W_proj)   (256 blocks: 32 row-panels x 8 col-96)
    gemm_fused<0><<<256, 512, 0, stream>>>(TH, TL, WTh, WTl,
                                           nullptr, nullptr, nullptr, X0h, X0l);

    // Stage C: 3 fused GCN layers (ping-pong X0 <-> X1)
    const u16* inh[3] = {X0h, X1h, X0h};
    const u16* inl[3] = {X0l, X1l, X0l};
    u16* outh[3] = {X1h, X0h, X1h};
    u16* outl[3] = {X1l, X0l, X1l};
    for (int l = 0; l < 3; ++l) {
        const size_t wo = (size_t)(l + 1) * D_ * D_;
        gemm_fused<1><<<256, 512, 0, stream>>>(inh[l], inl[l], WTh + wo, WTl + wo,
                                               ADJ, INV, bg[l], outh[l], outl[l]);
    }

    // Stage D: ragged node-span sum + head (final X lives in X1)
    gcn_target_kernel<<<B_, 192, 0, stream>>>(X1h, X1l, gspan, GT);
    head_kernel<<<B_, 256, 0, stream>>>(TMX, GT, fcW, fcb, out);
}